// Round 10
// baseline (231.075 us; speedup 1.0000x reference)
//
#include <hip/hip_runtime.h>

#define NN 1024
#define MM 1024
#define DD 256

typedef float floatx2 __attribute__((ext_vector_type(2)));

__device__ __forceinline__ float rcp_fast(float x) { return __builtin_amdgcn_rcpf(x); }

// ---------------- K1: fused dual GEMM + exp epilogue ----------------
// blocks 0..127:   q = f_r @ W_w^T + W_b    -> Eq[n][d]  = exp(2q)   (clamped +-5)
// blocks 128..255: k = f_rp @ Wp_w^T + Wp_b -> EkT[d][m] = exp(2k)   (LDS-transposed)
__global__ __launch_bounds__(256) void gemm_exp_kernel(
    const float* __restrict__ f_r,  const float* __restrict__ W_w,  const float* __restrict__ W_b,
    const float* __restrict__ f_rp, const float* __restrict__ Wp_w, const float* __restrict__ Wp_b,
    float* __restrict__ Eq, float* __restrict__ EkT, float* __restrict__ out0)
{
    __shared__ float As[32][36];
    __shared__ float Bs[32][68];
    __shared__ float T[64][36];

    const int b = blockIdx.x;
    const int t = threadIdx.x;
    if (b == 0) out0[t] = 0.f;

    const int mat  = b >> 7;
    const int tile = b & 127;
    const int rt = tile & 31, dt = tile >> 5;
    const float* __restrict__ A    = mat ? f_rp : f_r;
    const float* __restrict__ B    = mat ? Wp_w : W_w;
    const float* __restrict__ bias = mat ? Wp_b : W_b;

    const int tx = t & 15, ty = t >> 4;
    const int r0 = rt * 32, d0 = dt * 64;
    const int ar = t >> 3, ak = (t & 7) * 4;
    const int br = t >> 2, bk = (t & 3) * 8;

    float acc[2][4];
    #pragma unroll
    for (int i = 0; i < 2; ++i)
        #pragma unroll
        for (int j = 0; j < 4; ++j) acc[i][j] = 0.f;

    for (int kk = 0; kk < DD; kk += 32) {
        float4 av  = *(const float4*)(A + (size_t)(r0 + ar) * DD + kk + ak);
        float4 bv0 = *(const float4*)(B + (size_t)(d0 + br) * DD + kk + bk);
        float4 bv1 = *(const float4*)(B + (size_t)(d0 + br) * DD + kk + bk + 4);
        __syncthreads();
        As[ak + 0][ar] = av.x; As[ak + 1][ar] = av.y; As[ak + 2][ar] = av.z; As[ak + 3][ar] = av.w;
        Bs[bk + 0][br] = bv0.x; Bs[bk + 1][br] = bv0.y; Bs[bk + 2][br] = bv0.z; Bs[bk + 3][br] = bv0.w;
        Bs[bk + 4][br] = bv1.x; Bs[bk + 5][br] = bv1.y; Bs[bk + 6][br] = bv1.z; Bs[bk + 7][br] = bv1.w;
        __syncthreads();
        #pragma unroll
        for (int k = 0; k < 32; ++k) {
            float2 a2 = *(const float2*)&As[k][ty * 2];
            float4 b4 = *(const float4*)&Bs[k][tx * 4];
            float aa[2] = {a2.x, a2.y};
            float bb[4] = {b4.x, b4.y, b4.z, b4.w};
            #pragma unroll
            for (int i = 0; i < 2; ++i)
                #pragma unroll
                for (int j = 0; j < 4; ++j)
                    acc[i][j] = fmaf(aa[i], bb[j], acc[i][j]);
        }
    }

    float bj[4];
    #pragma unroll
    for (int j = 0; j < 4; ++j) bj[j] = bias[d0 + tx * 4 + j];

    float e[2][4];
    #pragma unroll
    for (int i = 0; i < 2; ++i)
        #pragma unroll
        for (int j = 0; j < 4; ++j) {
            float v = acc[i][j] + bj[j];
            // +-5: tanh(5)=0.9999092 (9e-5 error). 4-way product in K2:
            // x<=e^20, PT=x^4<=e^80=5.5e34 < fp32 max. (8-way hits e^160 -> inf.)
            v = fminf(fmaxf(v, -5.f), 5.f);
            e[i][j] = __expf(2.f * v);
        }

    if (mat == 0) {
        #pragma unroll
        for (int i = 0; i < 2; ++i)
            *(float4*)&Eq[(size_t)(r0 + ty * 2 + i) * DD + d0 + tx * 4] =
                make_float4(e[i][0], e[i][1], e[i][2], e[i][3]);
    } else {
        __syncthreads();
        #pragma unroll
        for (int i = 0; i < 2; ++i)
            #pragma unroll
            for (int j = 0; j < 4; ++j) T[tx * 4 + j][ty * 2 + i] = e[i][j];
        __syncthreads();
        const int dl = t >> 3, rl = (t & 7) * 4;
        #pragma unroll
        for (int h = 0; h < 2; ++h) {
            int dloc = dl + 32 * h;
            float4 tv = *(const float4*)&T[dloc][rl];
            *(float4*)&EkT[(size_t)(d0 + dloc) * MM + r0 + rl] = tv;
        }
    }
}

// ---------------- K2: mega — scores + softmax_M + context + stage-2 score ----------------
// R7 math verbatim; LDS dieted to ~64 KB (3-contributor accbuf unioned with a
// 32 KB ctxred) so 2 blocks/CU co-reside -> 8 waves/SIMD. q/w scalar loads
// software-pipelined one gi ahead.
__global__ __launch_bounds__(1024, 8) void fused_attn_kernel(
    const float* __restrict__ Eq, const float* __restrict__ EkT,
    const float* __restrict__ w_w, const float* __restrict__ frp,
    const float* __restrict__ wp_w,
    float* __restrict__ ctx, float* __restrict__ score)
{
    // union region: phase B accbuf (48 KB: [n][j][contrib][tm]) then
    // phase C ctxred (32 KB: [rr][n][256 floats]) — disjoint lifetimes.
    __shared__ float uni[12288];
    __shared__ float alsm[4][MM];          // 16 KB alpha (block-local)
    __shared__ float redmx[4][4];
    __shared__ float redsm[4][4];
    __shared__ float redsc[16];

    const int t  = threadIdx.x;
    const int tg = t >> 8;
    const int tm = t & 255;
    const int n0 = blockIdx.x * 4;

    const int dh = __builtin_amdgcn_readfirstlane(tg * 64);
    const float* __restrict__ eqb = Eq + (size_t)n0 * DD + dh;
    const float* __restrict__ wwb = w_w + dh;

    const floatx2 one2 = {1.f, 1.f};
    floatx2 accl[4] = {{0.f,0.f},{0.f,0.f},{0.f,0.f},{0.f,0.f}};
    floatx2 acch[4] = {{0.f,0.f},{0.f,0.f},{0.f,0.f},{0.f,0.f}};

    const float* ekb = EkT + (size_t)dh * MM + 4 * tm;
    float4 c0 = *(const float4*)(ekb + 0 * MM);
    float4 c1 = *(const float4*)(ekb + 1 * MM);
    float4 c2 = *(const float4*)(ekb + 2 * MM);
    float4 c3 = *(const float4*)(ekb + 3 * MM);

    // pipelined uniform q/w (scalar pipe)
    float4 wc = *(const float4*)(wwb);
    float4 qc[4];
    #pragma unroll
    for (int n = 0; n < 4; ++n) qc[n] = *(const float4*)(eqb + n * DD);

    for (int gi = 0; gi < 16; ++gi) {
        float4 p0 = c0, p1 = c1, p2 = c2, p3 = c3;
        float4 wn = wc, qn[4];
        #pragma unroll
        for (int n = 0; n < 4; ++n) qn[n] = qc[n];
        if (gi < 15) {
            const int dn = gi * 4 + 4;
            const float* nb = ekb + (size_t)dn * MM;
            p0 = *(const float4*)(nb + 0 * MM);
            p1 = *(const float4*)(nb + 1 * MM);
            p2 = *(const float4*)(nb + 2 * MM);
            p3 = *(const float4*)(nb + 3 * MM);
            wn = *(const float4*)(wwb + dn);
            #pragma unroll
            for (int n = 0; n < 4; ++n) qn[n] = *(const float4*)(eqb + n * DD + dn);
        }
        floatx2 k0l = {c0.x, c0.y}, k0h = {c0.z, c0.w};
        floatx2 k1l = {c1.x, c1.y}, k1h = {c1.z, c1.w};
        floatx2 k2l = {c2.x, c2.y}, k2h = {c2.z, c2.w};
        floatx2 k3l = {c3.x, c3.y}, k3h = {c3.z, c3.w};
        const float4 w4 = wc;
        #pragma unroll
        for (int n = 0; n < 4; ++n) {
            const float4 q4 = qc[n];
            #pragma unroll
            for (int h = 0; h < 2; ++h) {
                floatx2 x0 = q4.x * (h ? k0h : k0l) + one2;
                floatx2 x1 = q4.y * (h ? k1h : k1l) + one2;
                floatx2 x2 = q4.z * (h ? k2h : k2l) + one2;
                floatx2 x3 = q4.w * (h ? k3h : k3l) + one2;
                floatx2 p01 = x0 * x1;
                floatx2 p23 = x2 * x3;
                floatx2 n01 = w4.x * x1 + w4.y * x0;
                floatx2 n23 = w4.z * x3 + w4.w * x2;
                floatx2 nc  = n01 * p23 + n23 * p01;
                floatx2 pt  = p01 * p23;
                floatx2 r2;  r2.x = rcp_fast(pt.x);  r2.y = rcp_fast(pt.y);
                if (h == 0) accl[n] += nc * r2; else acch[n] += nc * r2;
            }
        }
        c0 = p0; c1 = p1; c2 = p2; c3 = p3;
        wc = wn;
        #pragma unroll
        for (int n = 0; n < 4; ++n) qc[n] = qn[n];
    }

    float acc[4][4];
    #pragma unroll
    for (int n = 0; n < 4; ++n) {
        acc[n][0] = -2.f * accl[n].x; acc[n][1] = -2.f * accl[n].y;
        acc[n][2] = -2.f * acch[n].x; acc[n][3] = -2.f * acch[n].y;
    }

    // ---- Phase B: 3-contributor combine + softmax; tg g owns row g ----
    // tg writes rows n != tg into slot [n][j][c][tm], c = tg<n ? tg : tg-1.
    #pragma unroll
    for (int n = 0; n < 4; ++n) {
        if (n == tg) continue;
        const int c = (tg < n) ? tg : tg - 1;
        #pragma unroll
        for (int j = 0; j < 4; ++j)
            uni[((n * 4 + j) * 3 + c) * 256 + tm] = acc[n][j];
    }
    __syncthreads();

    const int g = tg;
    const int w4id = (t >> 6) & 3;
    const int lane = t & 63;
    float aj[4];
    #pragma unroll
    for (int j = 0; j < 4; ++j)
        aj[j] = acc[g][j]
              + uni[((g * 4 + j) * 3 + 0) * 256 + tm]
              + uni[((g * 4 + j) * 3 + 1) * 256 + tm]
              + uni[((g * 4 + j) * 3 + 2) * 256 + tm];

    float mx = fmaxf(fmaxf(aj[0], aj[1]), fmaxf(aj[2], aj[3]));
    #pragma unroll
    for (int off = 32; off > 0; off >>= 1) mx = fmaxf(mx, __shfl_xor(mx, off));
    if (lane == 0) redmx[g][w4id] = mx;
    __syncthreads();
    const float MX = fmaxf(fmaxf(redmx[g][0], redmx[g][1]), fmaxf(redmx[g][2], redmx[g][3]));

    float e[4], sm = 0.f;
    #pragma unroll
    for (int j = 0; j < 4; ++j) { e[j] = __expf(aj[j] - MX); sm += e[j]; }
    #pragma unroll
    for (int off = 32; off > 0; off >>= 1) sm += __shfl_xor(sm, off);
    if (lane == 0) redsm[g][w4id] = sm;
    __syncthreads();
    const float S = redsm[g][0] + redsm[g][1] + redsm[g][2] + redsm[g][3];
    const float inv = rcp_fast(S);
    *(float4*)&alsm[g][4 * tm] = make_float4(e[0] * inv, e[1] * inv, e[2] * inv, e[3] * inv);
    __syncthreads();    // alpha ready; accbuf reads all done -> uni reusable

    // ---- Phase C: ctx = alpha @ frp; 8 m-ranges x 128 d-pairs ----
    const int cc = t & 127;       // d-pair: d = 2cc, 2cc+1
    const int rr = t >> 7;        // m-range rr*128 .. +127
    const int m0 = rr * 128;
    floatx2 ax[4] = {{0.f,0.f},{0.f,0.f},{0.f,0.f},{0.f,0.f}};
    const float* fb = frp + (size_t)m0 * DD + 2 * cc;
    for (int m4 = 0; m4 < 32; ++m4) {
        float alv[4][4];
        #pragma unroll
        for (int n = 0; n < 4; ++n) {
            float4 a4 = *(const float4*)&alsm[n][m0 + m4 * 4];
            alv[n][0] = a4.x; alv[n][1] = a4.y; alv[n][2] = a4.z; alv[n][3] = a4.w;
        }
        #pragma unroll
        for (int mm = 0; mm < 4; ++mm) {
            float2 f = *(const float2*)(fb + (size_t)(m4 * 4 + mm) * DD);
            floatx2 fv = {f.x, f.y};
            #pragma unroll
            for (int n = 0; n < 4; ++n) ax[n] += alv[n][mm] * fv;
        }
    }
    // ctxred[rr][n] = 256-float row; thread writes float2 at [2cc]
    #pragma unroll
    for (int n = 0; n < 4; ++n) {
        float2* row = (float2*)&uni[(rr * 4 + n) * 256];
        row[cc] = make_float2(ax[n].x, ax[n].y);
    }
    __syncthreads();

    const int nn = t >> 8, d = t & 255;
    float s = 0.f;
    #pragma unroll
    for (int r = 0; r < 8; ++r)
        s += uni[(r * 4 + nn) * 256 + d];
    ctx[(size_t)(n0 + nn) * DD + d] = s;

    float p = s * wp_w[d];
    #pragma unroll
    for (int off = 32; off > 0; off >>= 1) p += __shfl_xor(p, off);
    if (lane == 0) redsc[t >> 6] = p;
    __syncthreads();
    if (t < 4) score[n0 + t] = redsc[4 * t] + redsc[4 * t + 1] + redsc[4 * t + 2] + redsc[4 * t + 3];
}

// ---------------- K3: softmax over N (redundant per block) + pooled sum ----------------
__global__ __launch_bounds__(256) void pool_kernel(
    const float* __restrict__ ctx, const float* __restrict__ score,
    float* __restrict__ out)
{
    __shared__ float red[8];
    const int t = threadIdx.x, lane = t & 63, wid = t >> 6;
    const int n0 = blockIdx.x * 4;

    float s0 = score[t], s1 = score[t + 256], s2 = score[t + 512], s3 = score[t + 768];
    float mx = fmaxf(fmaxf(s0, s1), fmaxf(s2, s3));
    #pragma unroll
    for (int off = 32; off > 0; off >>= 1) mx = fmaxf(mx, __shfl_xor(mx, off));
    if (lane == 0) red[wid] = mx;
    __syncthreads();
    mx = fmaxf(fmaxf(red[0], red[1]), fmaxf(red[2], red[3]));

    float se = __expf(s0 - mx) + __expf(s1 - mx) + __expf(s2 - mx) + __expf(s3 - mx);
    #pragma unroll
    for (int off = 32; off > 0; off >>= 1) se += __shfl_xor(se, off);
    if (lane == 0) red[4 + wid] = se;
    __syncthreads();
    se = red[4] + red[5] + red[6] + red[7];
    float invS = rcp_fast(se);

    float r = 0.f;
    #pragma unroll
    for (int i = 0; i < 4; ++i) {
        float ap = __expf(score[n0 + i] - mx) * invS;
        r = fmaf(ap, ctx[(size_t)(n0 + i) * DD + t], r);
    }
    atomicAdd(out + t, r);
}

extern "C" void kernel_launch(void* const* d_in, const int* in_sizes, int n_in,
                              void* d_out, int out_size, void* d_ws, size_t ws_size,
                              hipStream_t stream) {
    const float* f_r  = (const float*)d_in[0];
    const float* f_rp = (const float*)d_in[1];
    const float* W_w  = (const float*)d_in[2];
    const float* W_b  = (const float*)d_in[3];
    const float* Wp_w = (const float*)d_in[4];
    const float* Wp_b = (const float*)d_in[5];
    const float* w_w  = (const float*)d_in[6];
    // d_in[7] = w_b  : cancels in softmax over m
    const float* wp_w = (const float*)d_in[8];
    // d_in[9] = wp_b : cancels in softmax over n
    float* out = (float*)d_out;

    float* ws    = (float*)d_ws;
    float* Eq    = ws;                  // 256K floats
    float* EkT   = ws + 262144;         // 256K
    float* ctx   = ws + 524288;         // 256K
    float* score = ws + 786432;         // 1K

    gemm_exp_kernel<<<256, 256, 0, stream>>>(f_r, W_w, W_b, f_rp, Wp_w, Wp_b, Eq, EkT, out);
    fused_attn_kernel<<<256, 1024, 0, stream>>>(Eq, EkT, w_w, f_rp, wp_w, ctx, score);
    pool_kernel<<<256, 256, 0, stream>>>(ctx, score, out);
}

// Round 11
// 150.456 us; speedup vs baseline: 1.5358x; 1.5358x over previous
//
#include <hip/hip_runtime.h>

#define NN 1024
#define MM 1024
#define DD 256

typedef float floatx2 __attribute__((ext_vector_type(2)));

__device__ __forceinline__ float rcp_fast(float x) { return __builtin_amdgcn_rcpf(x); }

// ---------------- K1: fused dual GEMM + exp epilogue ----------------
// blocks 0..127:   q = f_r @ W_w^T + W_b    -> Eq[n][d]  = exp(2q)   (clamped +-5)
// blocks 128..255: k = f_rp @ Wp_w^T + Wp_b -> EkT[d][m] = exp(2k)   (LDS-transposed)
__global__ __launch_bounds__(256) void gemm_exp_kernel(
    const float* __restrict__ f_r,  const float* __restrict__ W_w,  const float* __restrict__ W_b,
    const float* __restrict__ f_rp, const float* __restrict__ Wp_w, const float* __restrict__ Wp_b,
    float* __restrict__ Eq, float* __restrict__ EkT, float* __restrict__ out0)
{
    __shared__ float As[32][36];
    __shared__ float Bs[32][68];
    __shared__ float T[64][36];

    const int b = blockIdx.x;
    const int t = threadIdx.x;
    if (b == 0) out0[t] = 0.f;

    const int mat  = b >> 7;
    const int tile = b & 127;
    const int rt = tile & 31, dt = tile >> 5;
    const float* __restrict__ A    = mat ? f_rp : f_r;
    const float* __restrict__ B    = mat ? Wp_w : W_w;
    const float* __restrict__ bias = mat ? Wp_b : W_b;

    const int tx = t & 15, ty = t >> 4;
    const int r0 = rt * 32, d0 = dt * 64;
    const int ar = t >> 3, ak = (t & 7) * 4;
    const int br = t >> 2, bk = (t & 3) * 8;

    float acc[2][4];
    #pragma unroll
    for (int i = 0; i < 2; ++i)
        #pragma unroll
        for (int j = 0; j < 4; ++j) acc[i][j] = 0.f;

    for (int kk = 0; kk < DD; kk += 32) {
        float4 av  = *(const float4*)(A + (size_t)(r0 + ar) * DD + kk + ak);
        float4 bv0 = *(const float4*)(B + (size_t)(d0 + br) * DD + kk + bk);
        float4 bv1 = *(const float4*)(B + (size_t)(d0 + br) * DD + kk + bk + 4);
        __syncthreads();
        As[ak + 0][ar] = av.x; As[ak + 1][ar] = av.y; As[ak + 2][ar] = av.z; As[ak + 3][ar] = av.w;
        Bs[bk + 0][br] = bv0.x; Bs[bk + 1][br] = bv0.y; Bs[bk + 2][br] = bv0.z; Bs[bk + 3][br] = bv0.w;
        Bs[bk + 4][br] = bv1.x; Bs[bk + 5][br] = bv1.y; Bs[bk + 6][br] = bv1.z; Bs[bk + 7][br] = bv1.w;
        __syncthreads();
        #pragma unroll
        for (int k = 0; k < 32; ++k) {
            float2 a2 = *(const float2*)&As[k][ty * 2];
            float4 b4 = *(const float4*)&Bs[k][tx * 4];
            float aa[2] = {a2.x, a2.y};
            float bb[4] = {b4.x, b4.y, b4.z, b4.w};
            #pragma unroll
            for (int i = 0; i < 2; ++i)
                #pragma unroll
                for (int j = 0; j < 4; ++j)
                    acc[i][j] = fmaf(aa[i], bb[j], acc[i][j]);
        }
    }

    float bj[4];
    #pragma unroll
    for (int j = 0; j < 4; ++j) bj[j] = bias[d0 + tx * 4 + j];

    float e[2][4];
    #pragma unroll
    for (int i = 0; i < 2; ++i)
        #pragma unroll
        for (int j = 0; j < 4; ++j) {
            float v = acc[i][j] + bj[j];
            // +-5: tanh(5)=0.9999092 (9e-5 error). 4-way product in K2:
            // x<=e^20, PT=x^4<=e^80=5.5e34 < fp32 max. (8-way hits e^160 -> inf.)
            v = fminf(fmaxf(v, -5.f), 5.f);
            e[i][j] = __expf(2.f * v);
        }

    if (mat == 0) {
        #pragma unroll
        for (int i = 0; i < 2; ++i)
            *(float4*)&Eq[(size_t)(r0 + ty * 2 + i) * DD + d0 + tx * 4] =
                make_float4(e[i][0], e[i][1], e[i][2], e[i][3]);
    } else {
        __syncthreads();
        #pragma unroll
        for (int i = 0; i < 2; ++i)
            #pragma unroll
            for (int j = 0; j < 4; ++j) T[tx * 4 + j][ty * 2 + i] = e[i][j];
        __syncthreads();
        const int dl = t >> 3, rl = (t & 7) * 4;
        #pragma unroll
        for (int h = 0; h < 2; ++h) {
            int dloc = dl + 32 * h;
            float4 tv = *(const float4*)&T[dloc][rl];
            *(float4*)&EkT[(size_t)(d0 + dloc) * MM + r0 + rl] = tv;
        }
    }
}

// ---------------- K2: mega — scores + softmax_M + context + stage-2 score ----------------
// R7 math; LDS dieted (48 KB union + 16 KB alpha) for 2 blocks/CU; phase A has
// MINIMAL live registers (no prefetch rotation — TLP from 8 waves/SIMD hides
// latency; q/w are scalar s_load). Goal: VGPR <= 64, no scratch.
__global__ __launch_bounds__(1024, 8) void fused_attn_kernel(
    const float* __restrict__ Eq, const float* __restrict__ EkT,
    const float* __restrict__ w_w, const float* __restrict__ frp,
    const float* __restrict__ wp_w,
    float* __restrict__ ctx, float* __restrict__ score)
{
    // union: phase B accbuf (48 KB: [n*4+j][contrib][tm]) then phase C
    // ctxred (32 KB: [(rr*4+n)*256 + d]) — disjoint lifetimes.
    __shared__ float uni[12288];
    __shared__ float alsm[4][MM];          // 16 KB alpha (block-local)
    __shared__ float redmx[4][4];
    __shared__ float redsm[4][4];
    __shared__ float redsc[16];

    const int t  = threadIdx.x;
    const int tg = t >> 8;
    const int tm = t & 255;
    const int n0 = blockIdx.x * 4;

    const int dh = __builtin_amdgcn_readfirstlane(tg * 64);
    const float* __restrict__ eqb = Eq + (size_t)n0 * DD + dh;   // scalar base
    const float* __restrict__ wwb = w_w + dh;                    // scalar base

    const floatx2 one2 = {1.f, 1.f};
    floatx2 accl[4] = {{0.f,0.f},{0.f,0.f},{0.f,0.f},{0.f,0.f}};
    floatx2 acch[4] = {{0.f,0.f},{0.f,0.f},{0.f,0.f},{0.f,0.f}};

    const float* ekb = EkT + (size_t)dh * MM + 4 * tm;

    for (int gi = 0; gi < 16; ++gi) {
        const int db = gi * 4;
        const float* rb = ekb + (size_t)db * MM;
        float4 c0 = *(const float4*)(rb + 0 * MM);
        float4 c1 = *(const float4*)(rb + 1 * MM);
        float4 c2 = *(const float4*)(rb + 2 * MM);
        float4 c3 = *(const float4*)(rb + 3 * MM);
        float4 w4 = *(const float4*)(wwb + db);            // uniform -> s_load
        floatx2 k0l = {c0.x, c0.y}, k0h = {c0.z, c0.w};
        floatx2 k1l = {c1.x, c1.y}, k1h = {c1.z, c1.w};
        floatx2 k2l = {c2.x, c2.y}, k2h = {c2.z, c2.w};
        floatx2 k3l = {c3.x, c3.y}, k3h = {c3.z, c3.w};
        #pragma unroll
        for (int n = 0; n < 4; ++n) {
            const float4 q4 = *(const float4*)(eqb + n * DD + db);   // uniform -> s_load
            #pragma unroll
            for (int h = 0; h < 2; ++h) {
                floatx2 x0 = q4.x * (h ? k0h : k0l) + one2;
                floatx2 x1 = q4.y * (h ? k1h : k1l) + one2;
                floatx2 x2 = q4.z * (h ? k2h : k2l) + one2;
                floatx2 x3 = q4.w * (h ? k3h : k3l) + one2;
                floatx2 p01 = x0 * x1;
                floatx2 p23 = x2 * x3;
                floatx2 n01 = w4.x * x1 + w4.y * x0;
                floatx2 n23 = w4.z * x3 + w4.w * x2;
                floatx2 nc  = n01 * p23 + n23 * p01;
                floatx2 pt  = p01 * p23;
                floatx2 r2;  r2.x = rcp_fast(pt.x);  r2.y = rcp_fast(pt.y);
                if (h == 0) accl[n] += nc * r2; else acch[n] += nc * r2;
            }
        }
    }

    float acc[4][4];
    #pragma unroll
    for (int n = 0; n < 4; ++n) {
        acc[n][0] = -2.f * accl[n].x; acc[n][1] = -2.f * accl[n].y;
        acc[n][2] = -2.f * acch[n].x; acc[n][3] = -2.f * acch[n].y;
    }

    // ---- Phase B: 3-contributor combine + softmax; tg g owns row g ----
    #pragma unroll
    for (int n = 0; n < 4; ++n) {
        if (n == tg) continue;
        const int c = (tg < n) ? tg : tg - 1;
        #pragma unroll
        for (int j = 0; j < 4; ++j)
            uni[((n * 4 + j) * 3 + c) * 256 + tm] = acc[n][j];
    }
    __syncthreads();

    const int g = tg;
    const int w4id = (t >> 6) & 3;
    const int lane = t & 63;
    float aj[4];
    #pragma unroll
    for (int j = 0; j < 4; ++j)
        aj[j] = acc[g][j]
              + uni[((g * 4 + j) * 3 + 0) * 256 + tm]
              + uni[((g * 4 + j) * 3 + 1) * 256 + tm]
              + uni[((g * 4 + j) * 3 + 2) * 256 + tm];

    float mx = fmaxf(fmaxf(aj[0], aj[1]), fmaxf(aj[2], aj[3]));
    #pragma unroll
    for (int off = 32; off > 0; off >>= 1) mx = fmaxf(mx, __shfl_xor(mx, off));
    if (lane == 0) redmx[g][w4id] = mx;
    __syncthreads();
    const float MX = fmaxf(fmaxf(redmx[g][0], redmx[g][1]), fmaxf(redmx[g][2], redmx[g][3]));

    float e[4], sm = 0.f;
    #pragma unroll
    for (int j = 0; j < 4; ++j) { e[j] = __expf(aj[j] - MX); sm += e[j]; }
    #pragma unroll
    for (int off = 32; off > 0; off >>= 1) sm += __shfl_xor(sm, off);
    if (lane == 0) redsm[g][w4id] = sm;
    __syncthreads();
    const float S = redsm[g][0] + redsm[g][1] + redsm[g][2] + redsm[g][3];
    const float inv = rcp_fast(S);
    *(float4*)&alsm[g][4 * tm] = make_float4(e[0] * inv, e[1] * inv, e[2] * inv, e[3] * inv);
    __syncthreads();    // alpha ready; accbuf reads done -> uni reusable

    // ---- Phase C: ctx = alpha @ frp; 8 m-ranges x 128 d-pairs ----
    const int cc = t & 127;       // d-pair: d = 2cc, 2cc+1
    const int rr = t >> 7;        // m-range rr*128 .. +127
    const int m0 = rr * 128;
    floatx2 ax[4] = {{0.f,0.f},{0.f,0.f},{0.f,0.f},{0.f,0.f}};
    const float* fb = frp + (size_t)m0 * DD + 2 * cc;
    for (int m4 = 0; m4 < 32; ++m4) {
        float alv[4][4];
        #pragma unroll
        for (int n = 0; n < 4; ++n) {
            float4 a4 = *(const float4*)&alsm[n][m0 + m4 * 4];
            alv[n][0] = a4.x; alv[n][1] = a4.y; alv[n][2] = a4.z; alv[n][3] = a4.w;
        }
        #pragma unroll
        for (int mm = 0; mm < 4; ++mm) {
            float2 f = *(const float2*)(fb + (size_t)(m4 * 4 + mm) * DD);
            floatx2 fv = {f.x, f.y};
            #pragma unroll
            for (int n = 0; n < 4; ++n) ax[n] += alv[n][mm] * fv;
        }
    }
    #pragma unroll
    for (int n = 0; n < 4; ++n) {
        float2* row = (float2*)&uni[(rr * 4 + n) * 256];
        row[cc] = make_float2(ax[n].x, ax[n].y);
    }
    __syncthreads();

    const int nn = t >> 8, d = t & 255;
    float s = 0.f;
    #pragma unroll
    for (int r = 0; r < 8; ++r)
        s += uni[(r * 4 + nn) * 256 + d];
    ctx[(size_t)(n0 + nn) * DD + d] = s;

    float p = s * wp_w[d];
    #pragma unroll
    for (int off = 32; off > 0; off >>= 1) p += __shfl_xor(p, off);
    if (lane == 0) redsc[t >> 6] = p;
    __syncthreads();
    if (t < 4) score[n0 + t] = redsc[4 * t] + redsc[4 * t + 1] + redsc[4 * t + 2] + redsc[4 * t + 3];
}

// ---------------- K3: softmax over N (redundant per block) + pooled sum ----------------
__global__ __launch_bounds__(256) void pool_kernel(
    const float* __restrict__ ctx, const float* __restrict__ score,
    float* __restrict__ out)
{
    __shared__ float red[8];
    const int t = threadIdx.x, lane = t & 63, wid = t >> 6;
    const int n0 = blockIdx.x * 4;

    float s0 = score[t], s1 = score[t + 256], s2 = score[t + 512], s3 = score[t + 768];
    float mx = fmaxf(fmaxf(s0, s1), fmaxf(s2, s3));
    #pragma unroll
    for (int off = 32; off > 0; off >>= 1) mx = fmaxf(mx, __shfl_xor(mx, off));
    if (lane == 0) red[wid] = mx;
    __syncthreads();
    mx = fmaxf(fmaxf(red[0], red[1]), fmaxf(red[2], red[3]));

    float se = __expf(s0 - mx) + __expf(s1 - mx) + __expf(s2 - mx) + __expf(s3 - mx);
    #pragma unroll
    for (int off = 32; off > 0; off >>= 1) se += __shfl_xor(se, off);
    if (lane == 0) red[4 + wid] = se;
    __syncthreads();
    se = red[4] + red[5] + red[6] + red[7];
    float invS = rcp_fast(se);

    float r = 0.f;
    #pragma unroll
    for (int i = 0; i < 4; ++i) {
        float ap = __expf(score[n0 + i] - mx) * invS;
        r = fmaf(ap, ctx[(size_t)(n0 + i) * DD + t], r);
    }
    atomicAdd(out + t, r);
}

extern "C" void kernel_launch(void* const* d_in, const int* in_sizes, int n_in,
                              void* d_out, int out_size, void* d_ws, size_t ws_size,
                              hipStream_t stream) {
    const float* f_r  = (const float*)d_in[0];
    const float* f_rp = (const float*)d_in[1];
    const float* W_w  = (const float*)d_in[2];
    const float* W_b  = (const float*)d_in[3];
    const float* Wp_w = (const float*)d_in[4];
    const float* Wp_b = (const float*)d_in[5];
    const float* w_w  = (const float*)d_in[6];
    // d_in[7] = w_b  : cancels in softmax over m
    const float* wp_w = (const float*)d_in[8];
    // d_in[9] = wp_b : cancels in softmax over n
    float* out = (float*)d_out;

    float* ws    = (float*)d_ws;
    float* Eq    = ws;                  // 256K floats
    float* EkT   = ws + 262144;         // 256K
    float* ctx   = ws + 524288;         // 256K
    float* score = ws + 786432;         // 1K

    gemm_exp_kernel<<<256, 256, 0, stream>>>(f_r, W_w, W_b, f_rp, Wp_w, Wp_b, Eq, EkT, out);
    fused_attn_kernel<<<256, 1024, 0, stream>>>(Eq, EkT, w_w, f_rp, wp_w, ctx, score);
    pool_kernel<<<256, 256, 0, stream>>>(ctx, score, out);
}

// Round 12
// 144.575 us; speedup vs baseline: 1.5983x; 1.0407x over previous
//
#include <hip/hip_runtime.h>

#define NN 1024
#define MM 1024
#define DD 256

typedef float floatx2 __attribute__((ext_vector_type(2)));

__device__ __forceinline__ float rcp_fast(float x) { return __builtin_amdgcn_rcpf(x); }

// ---------------- K1: fused dual GEMM + exp epilogue ----------------
// blocks 0..127:   q = f_r @ W_w^T + W_b    -> Eq[n][d]  = exp(2q)   (clamped +-5)
// blocks 128..255: k = f_rp @ Wp_w^T + Wp_b -> EkT[d][m] = exp(2k)   (LDS-transposed)
__global__ __launch_bounds__(256) void gemm_exp_kernel(
    const float* __restrict__ f_r,  const float* __restrict__ W_w,  const float* __restrict__ W_b,
    const float* __restrict__ f_rp, const float* __restrict__ Wp_w, const float* __restrict__ Wp_b,
    float* __restrict__ Eq, float* __restrict__ EkT, float* __restrict__ out0)
{
    __shared__ float As[32][36];
    __shared__ float Bs[32][68];
    __shared__ float T[64][36];

    const int b = blockIdx.x;
    const int t = threadIdx.x;
    if (b == 0) out0[t] = 0.f;

    const int mat  = b >> 7;
    const int tile = b & 127;
    const int rt = tile & 31, dt = tile >> 5;
    const float* __restrict__ A    = mat ? f_rp : f_r;
    const float* __restrict__ B    = mat ? Wp_w : W_w;
    const float* __restrict__ bias = mat ? Wp_b : W_b;

    const int tx = t & 15, ty = t >> 4;
    const int r0 = rt * 32, d0 = dt * 64;
    const int ar = t >> 3, ak = (t & 7) * 4;
    const int br = t >> 2, bk = (t & 3) * 8;

    float acc[2][4];
    #pragma unroll
    for (int i = 0; i < 2; ++i)
        #pragma unroll
        for (int j = 0; j < 4; ++j) acc[i][j] = 0.f;

    for (int kk = 0; kk < DD; kk += 32) {
        float4 av  = *(const float4*)(A + (size_t)(r0 + ar) * DD + kk + ak);
        float4 bv0 = *(const float4*)(B + (size_t)(d0 + br) * DD + kk + bk);
        float4 bv1 = *(const float4*)(B + (size_t)(d0 + br) * DD + kk + bk + 4);
        __syncthreads();
        As[ak + 0][ar] = av.x; As[ak + 1][ar] = av.y; As[ak + 2][ar] = av.z; As[ak + 3][ar] = av.w;
        Bs[bk + 0][br] = bv0.x; Bs[bk + 1][br] = bv0.y; Bs[bk + 2][br] = bv0.z; Bs[bk + 3][br] = bv0.w;
        Bs[bk + 4][br] = bv1.x; Bs[bk + 5][br] = bv1.y; Bs[bk + 6][br] = bv1.z; Bs[bk + 7][br] = bv1.w;
        __syncthreads();
        #pragma unroll
        for (int k = 0; k < 32; ++k) {
            float2 a2 = *(const float2*)&As[k][ty * 2];
            float4 b4 = *(const float4*)&Bs[k][tx * 4];
            float aa[2] = {a2.x, a2.y};
            float bb[4] = {b4.x, b4.y, b4.z, b4.w};
            #pragma unroll
            for (int i = 0; i < 2; ++i)
                #pragma unroll
                for (int j = 0; j < 4; ++j)
                    acc[i][j] = fmaf(aa[i], bb[j], acc[i][j]);
        }
    }

    float bj[4];
    #pragma unroll
    for (int j = 0; j < 4; ++j) bj[j] = bias[d0 + tx * 4 + j];

    float e[2][4];
    #pragma unroll
    for (int i = 0; i < 2; ++i)
        #pragma unroll
        for (int j = 0; j < 4; ++j) {
            float v = acc[i][j] + bj[j];
            // +-5: tanh(5)=0.9999092 (9e-5 error). 4-way product in K2:
            // x<=e^20, PT=x^4<=e^80=5.5e34 < fp32 max. (8-way hits e^160 -> inf.)
            v = fminf(fmaxf(v, -5.f), 5.f);
            e[i][j] = __expf(2.f * v);
        }

    if (mat == 0) {
        #pragma unroll
        for (int i = 0; i < 2; ++i)
            *(float4*)&Eq[(size_t)(r0 + ty * 2 + i) * DD + d0 + tx * 4] =
                make_float4(e[i][0], e[i][1], e[i][2], e[i][3]);
    } else {
        __syncthreads();
        #pragma unroll
        for (int i = 0; i < 2; ++i)
            #pragma unroll
            for (int j = 0; j < 4; ++j) T[tx * 4 + j][ty * 2 + i] = e[i][j];
        __syncthreads();
        const int dl = t >> 3, rl = (t & 7) * 4;
        #pragma unroll
        for (int h = 0; h < 2; ++h) {
            int dloc = dl + 32 * h;
            float4 tv = *(const float4*)&T[dloc][rl];
            *(float4*)&EkT[(size_t)(d0 + dloc) * MM + r0 + rl] = tv;
        }
    }
}

// ---------------- K2: mega — scores + softmax_M + context + stage-2 score ----------------
// 512 blocks x 1024 thr; block = 2 n-rows (doubles grid -> 2 blocks/CU co-resident
// -> 8 waves/SIMD; R11's 256-block grid could never use its occupancy headroom).
// tg = t>>8 = d-quarter; tm = t&255 -> m cols 4tm..4tm+3. Minimal live VGPR in
// phase A (TLP hides latency; q/w are scalar s_load).
__global__ __launch_bounds__(1024, 8) void fused_attn_kernel(
    const float* __restrict__ Eq, const float* __restrict__ EkT,
    const float* __restrict__ w_w, const float* __restrict__ frp,
    const float* __restrict__ wp_w,
    float* __restrict__ ctx, float* __restrict__ score)
{
    // union: phase B accbuf (32 KB: [(n*4+j)*4+tg][tm]) then phase C
    // ctxred (16 KB: [(rr*2+n)*256 + d]) — disjoint lifetimes.
    __shared__ float uni[8192];
    __shared__ float alsm[2][MM];          // 8 KB alpha (block-local)
    __shared__ float redmx[2][4];
    __shared__ float redsm[2][4];
    __shared__ float redsc[8];

    const int t  = threadIdx.x;
    const int tg = t >> 8;
    const int tm = t & 255;
    const int n0 = blockIdx.x * 2;

    const int dh = __builtin_amdgcn_readfirstlane(tg * 64);
    const float* __restrict__ eqb = Eq + (size_t)n0 * DD + dh;   // scalar base
    const float* __restrict__ wwb = w_w + dh;                    // scalar base

    const floatx2 one2 = {1.f, 1.f};
    floatx2 accl[2] = {{0.f,0.f},{0.f,0.f}};
    floatx2 acch[2] = {{0.f,0.f},{0.f,0.f}};

    const float* ekb = EkT + (size_t)dh * MM + 4 * tm;

    for (int gi = 0; gi < 16; ++gi) {
        const int db = gi * 4;
        const float* rb = ekb + (size_t)db * MM;
        float4 c0 = *(const float4*)(rb + 0 * MM);
        float4 c1 = *(const float4*)(rb + 1 * MM);
        float4 c2 = *(const float4*)(rb + 2 * MM);
        float4 c3 = *(const float4*)(rb + 3 * MM);
        float4 w4 = *(const float4*)(wwb + db);            // uniform -> s_load
        floatx2 k0l = {c0.x, c0.y}, k0h = {c0.z, c0.w};
        floatx2 k1l = {c1.x, c1.y}, k1h = {c1.z, c1.w};
        floatx2 k2l = {c2.x, c2.y}, k2h = {c2.z, c2.w};
        floatx2 k3l = {c3.x, c3.y}, k3h = {c3.z, c3.w};
        #pragma unroll
        for (int n = 0; n < 2; ++n) {
            const float4 q4 = *(const float4*)(eqb + n * DD + db);   // uniform -> s_load
            #pragma unroll
            for (int h = 0; h < 2; ++h) {
                floatx2 x0 = q4.x * (h ? k0h : k0l) + one2;
                floatx2 x1 = q4.y * (h ? k1h : k1l) + one2;
                floatx2 x2 = q4.z * (h ? k2h : k2l) + one2;
                floatx2 x3 = q4.w * (h ? k3h : k3l) + one2;
                floatx2 p01 = x0 * x1;
                floatx2 p23 = x2 * x3;
                floatx2 n01 = w4.x * x1 + w4.y * x0;
                floatx2 n23 = w4.z * x3 + w4.w * x2;
                floatx2 nc  = n01 * p23 + n23 * p01;
                floatx2 pt  = p01 * p23;
                floatx2 r2;  r2.x = rcp_fast(pt.x);  r2.y = rcp_fast(pt.y);
                if (h == 0) accl[n] += nc * r2; else acch[n] += nc * r2;
            }
        }
    }

    float acc[2][4];
    #pragma unroll
    for (int n = 0; n < 2; ++n) {
        acc[n][0] = -2.f * accl[n].x; acc[n][1] = -2.f * accl[n].y;
        acc[n][2] = -2.f * acch[n].x; acc[n][3] = -2.f * acch[n].y;
    }

    // ---- Phase B: 4-slab combine + softmax; tg 0/1 own rows 0/1 ----
    #pragma unroll
    for (int n = 0; n < 2; ++n)
        #pragma unroll
        for (int j = 0; j < 4; ++j)
            uni[((n * 4 + j) * 4 + tg) * 256 + tm] = acc[n][j];
    __syncthreads();

    const int w4id = (t >> 6) & 3;     // wave index within tg group
    const int lane = t & 63;
    if (tg < 2) {
        const int g = tg;              // owned row
        float aj[4];
        #pragma unroll
        for (int j = 0; j < 4; ++j)
            aj[j] = uni[((g * 4 + j) * 4 + 0) * 256 + tm]
                  + uni[((g * 4 + j) * 4 + 1) * 256 + tm]
                  + uni[((g * 4 + j) * 4 + 2) * 256 + tm]
                  + uni[((g * 4 + j) * 4 + 3) * 256 + tm];

        float mx = fmaxf(fmaxf(aj[0], aj[1]), fmaxf(aj[2], aj[3]));
        #pragma unroll
        for (int off = 32; off > 0; off >>= 1) mx = fmaxf(mx, __shfl_xor(mx, off));
        if (lane == 0) redmx[g][w4id] = mx;
        __syncthreads();
        const float MX = fmaxf(fmaxf(redmx[g][0], redmx[g][1]), fmaxf(redmx[g][2], redmx[g][3]));

        float e[4], sm = 0.f;
        #pragma unroll
        for (int j = 0; j < 4; ++j) { e[j] = __expf(aj[j] - MX); sm += e[j]; }
        #pragma unroll
        for (int off = 32; off > 0; off >>= 1) sm += __shfl_xor(sm, off);
        if (lane == 0) redsm[g][w4id] = sm;
        __syncthreads();
        const float S = redsm[g][0] + redsm[g][1] + redsm[g][2] + redsm[g][3];
        const float inv = rcp_fast(S);
        *(float4*)&alsm[g][4 * tm] = make_float4(e[0] * inv, e[1] * inv, e[2] * inv, e[3] * inv);
    } else {
        __syncthreads();   // match owner barriers (wave-uniform branch: tg per 4 waves)
        __syncthreads();
    }
    __syncthreads();    // alpha ready; accbuf reads done -> uni reusable

    // ---- Phase C: ctx = alpha @ frp; 8 m-ranges x 128 d-pairs, 2 rows ----
    const int cc = t & 127;       // d-pair: d = 2cc, 2cc+1
    const int rr = t >> 7;        // m-range rr*128 .. +127
    const int m0 = rr * 128;
    floatx2 ax[2] = {{0.f,0.f},{0.f,0.f}};
    const float* fb = frp + (size_t)m0 * DD + 2 * cc;
    for (int m4 = 0; m4 < 32; ++m4) {
        float alv[2][4];
        #pragma unroll
        for (int n = 0; n < 2; ++n) {
            float4 a4 = *(const float4*)&alsm[n][m0 + m4 * 4];
            alv[n][0] = a4.x; alv[n][1] = a4.y; alv[n][2] = a4.z; alv[n][3] = a4.w;
        }
        #pragma unroll
        for (int mm = 0; mm < 4; ++mm) {
            float2 f = *(const float2*)(fb + (size_t)(m4 * 4 + mm) * DD);
            floatx2 fv = {f.x, f.y};
            #pragma unroll
            for (int n = 0; n < 2; ++n) ax[n] += alv[n][mm] * fv;
        }
    }
    #pragma unroll
    for (int n = 0; n < 2; ++n) {
        float2* row = (float2*)&uni[(rr * 2 + n) * 256];
        row[cc] = make_float2(ax[n].x, ax[n].y);
    }
    __syncthreads();

    if (t < 512) {
        const int nn = t >> 8, d = t & 255;
        float s = 0.f;
        #pragma unroll
        for (int r = 0; r < 8; ++r)
            s += uni[(r * 2 + nn) * 256 + d];
        ctx[(size_t)(n0 + nn) * DD + d] = s;

        float p = s * wp_w[d];
        #pragma unroll
        for (int off = 32; off > 0; off >>= 1) p += __shfl_xor(p, off);
        if (lane == 0) redsc[t >> 6] = p;
    }
    __syncthreads();
    if (t < 2) score[n0 + t] = redsc[4 * t] + redsc[4 * t + 1] + redsc[4 * t + 2] + redsc[4 * t + 3];
}

// ---------------- K3: softmax over N (redundant per block) + pooled sum ----------------
__global__ __launch_bounds__(256) void pool_kernel(
    const float* __restrict__ ctx, const float* __restrict__ score,
    float* __restrict__ out)
{
    __shared__ float red[8];
    const int t = threadIdx.x, lane = t & 63, wid = t >> 6;
    const int n0 = blockIdx.x * 4;

    float s0 = score[t], s1 = score[t + 256], s2 = score[t + 512], s3 = score[t + 768];
    float mx = fmaxf(fmaxf(s0, s1), fmaxf(s2, s3));
    #pragma unroll
    for (int off = 32; off > 0; off >>= 1) mx = fmaxf(mx, __shfl_xor(mx, off));
    if (lane == 0) red[wid] = mx;
    __syncthreads();
    mx = fmaxf(fmaxf(red[0], red[1]), fmaxf(red[2], red[3]));

    float se = __expf(s0 - mx) + __expf(s1 - mx) + __expf(s2 - mx) + __expf(s3 - mx);
    #pragma unroll
    for (int off = 32; off > 0; off >>= 1) se += __shfl_xor(se, off);
    if (lane == 0) red[4 + wid] = se;
    __syncthreads();
    se = red[4] + red[5] + red[6] + red[7];
    float invS = rcp_fast(se);

    float r = 0.f;
    #pragma unroll
    for (int i = 0; i < 4; ++i) {
        float ap = __expf(score[n0 + i] - mx) * invS;
        r = fmaf(ap, ctx[(size_t)(n0 + i) * DD + t], r);
    }
    atomicAdd(out + t, r);
}

extern "C" void kernel_launch(void* const* d_in, const int* in_sizes, int n_in,
                              void* d_out, int out_size, void* d_ws, size_t ws_size,
                              hipStream_t stream) {
    const float* f_r  = (const float*)d_in[0];
    const float* f_rp = (const float*)d_in[1];
    const float* W_w  = (const float*)d_in[2];
    const float* W_b  = (const float*)d_in[3];
    const float* Wp_w = (const float*)d_in[4];
    const float* Wp_b = (const float*)d_in[5];
    const float* w_w  = (const float*)d_in[6];
    // d_in[7] = w_b  : cancels in softmax over m
    const float* wp_w = (const float*)d_in[8];
    // d_in[9] = wp_b : cancels in softmax over n
    float* out = (float*)d_out;

    float* ws    = (float*)d_ws;
    float* Eq    = ws;                  // 256K floats
    float* EkT   = ws + 262144;         // 256K
    float* ctx   = ws + 524288;         // 256K
    float* score = ws + 786432;         // 1K

    gemm_exp_kernel<<<256, 256, 0, stream>>>(f_r, W_w, W_b, f_rp, Wp_w, Wp_b, Eq, EkT, out);
    fused_attn_kernel<<<512, 1024, 0, stream>>>(Eq, EkT, w_w, f_rp, wp_w, ctx, score);
    pool_kernel<<<256, 256, 0, stream>>>(ctx, score, out);
}